// Round 5
// baseline (123.135 us; speedup 1.0000x reference)
//
#include <hip/hip_runtime.h>
#include <hip/hip_bf16.h>

#define BB 8
#define NN 1024
#define FIN 256
#define FOUT 256
#define NH 4
#define CAP 192    // max nnz per adjacency row (mean 51, 20 sigma margin)

typedef short short8 __attribute__((ext_vector_type(8)));
typedef short short4v __attribute__((ext_vector_type(4)));
typedef float floatx4 __attribute__((ext_vector_type(4)));

__device__ __forceinline__ short f2bf(float f) {
    unsigned int u = __builtin_bit_cast(unsigned int, f);
    unsigned int r = (u + 0x7fffu + ((u >> 16) & 1u)) >> 16;   // RNE
    return (short)r;
}
__device__ __forceinline__ float bf2f(unsigned short s) {
    return __builtin_bit_cast(float, (unsigned int)s << 16);
}

// ---------------- Kernel 0: Wt[n][k] = bf16(W[k][n])  (256x256, 128 KB out) ----------
__global__ __launch_bounds__(256) void k_wt(const float* __restrict__ W,
                                            unsigned short* __restrict__ Wt) {
    __shared__ unsigned short ts[64][80];   // [n][k], pad 80 -> 16B-aligned rows
    const int k0 = blockIdx.x * 64, n0 = blockIdx.y * 64;
    const int t = threadIdx.x;
#pragma unroll
    for (int q = 0; q < 4; ++q) {
        int lin = t + q * 256;              // 0..1023 float4s
        int r = lin >> 4, c4 = lin & 15;    // r = k row, c4 = n group
        float4 v = *(const float4*)&W[(size_t)(k0 + r) * FOUT + n0 + c4 * 4];
        ts[c4 * 4 + 0][r] = (unsigned short)f2bf(v.x);
        ts[c4 * 4 + 1][r] = (unsigned short)f2bf(v.y);
        ts[c4 * 4 + 2][r] = (unsigned short)f2bf(v.z);
        ts[c4 * 4 + 3][r] = (unsigned short)f2bf(v.w);
    }
    __syncthreads();
#pragma unroll
    for (int q = 0; q < 2; ++q) {
        int lin = t + q * 256;              // 0..511 short8s
        int row = lin >> 3, kg = lin & 7;
        short8 s = *(short8*)&ts[row][kg * 8];
        *(short8*)&Wt[(size_t)(n0 + row) * FIN + k0 + kg * 8] = s;
    }
}

// ---------------- Kernel 1: fused h=x@W (bf16 MFMA) + LayerNorm + e_src/e_dst --------
// Block: 16 rows x 256 cols, 512 threads (8 waves). Wave w owns cols [32w,32w+32).
__global__ __launch_bounds__(512) void k_gemm_ln(const float* __restrict__ x,
                                                 const unsigned short* __restrict__ Wt,
                                                 const float* __restrict__ gamma,
                                                 const float* __restrict__ beta,
                                                 const float* __restrict__ a,
                                                 unsigned short* __restrict__ hb,
                                                 float* __restrict__ e_src,
                                                 float* __restrict__ e_dst) {
    __shared__ unsigned short As[16 * 264];   // [m][k] stride 264 (8.4 KB)
    __shared__ float sumL[8][16], sqL[8][16];
    __shared__ float pesL[8][16], pedL[8][16];
    const int m0 = blockIdx.x * 16;
    const int t = threadIdx.x;
    const int w = t >> 6, lane = t & 63, quad = lane >> 4, l15 = lane & 15;

    // stage A: 16 x 256 fp32 -> bf16 (coalesced float4)
#pragma unroll
    for (int q = 0; q < 2; ++q) {
        int lin = t + q * 512;               // 0..1023 float4
        int row = lin >> 6, c4 = lin & 63;
        float4 v = *(const float4*)&x[(size_t)(m0 + row) * FIN + c4 * 4];
        short4v s;
        s.x = f2bf(v.x); s.y = f2bf(v.y); s.z = f2bf(v.z); s.w = f2bf(v.w);
        *(short4v*)&As[row * 264 + c4 * 4] = s;
    }
    __syncthreads();

    floatx4 acc[2];
#pragma unroll
    for (int nt = 0; nt < 2; ++nt) acc[nt] = (floatx4)0.f;

#pragma unroll
    for (int ks = 0; ks < 8; ++ks) {
        short8 af = *(short8*)&As[l15 * 264 + ks * 32 + quad * 8];
#pragma unroll
        for (int nt = 0; nt < 2; ++nt) {
            short8 bf = *(const short8*)&Wt[(size_t)((w * 2 + nt) * 16 + l15) * FIN + ks * 32 + quad * 8];
            acc[nt] = __builtin_amdgcn_mfma_f32_16x16x32_bf16(af, bf, acc[nt], 0, 0, 0);
        }
    }

    // per-wave LN partials: row = quad*4+reg, this wave's 32 cols
    float rs[4], rq[4];
#pragma unroll
    for (int reg = 0; reg < 4; ++reg) {
        float s = 0.f, q2 = 0.f;
#pragma unroll
        for (int nt = 0; nt < 2; ++nt) { float v = acc[nt][reg]; s += v; q2 = fmaf(v, v, q2); }
#pragma unroll
        for (int off = 1; off < 16; off <<= 1) { s += __shfl_xor(s, off); q2 += __shfl_xor(q2, off); }
        rs[reg] = s; rq[reg] = q2;
    }
    if (l15 == 0) {
#pragma unroll
        for (int reg = 0; reg < 4; ++reg) {
            sumL[w][quad * 4 + reg] = rs[reg];
            sqL[w][quad * 4 + reg] = rq[reg];
        }
    }
    __syncthreads();   // also separates K-loop As reads from hn overwrite below

    float g[2], bt[2], as_[2], ad_[2];
#pragma unroll
    for (int nt = 0; nt < 2; ++nt) {
        int col = w * 32 + nt * 16 + l15;
        g[nt] = gamma[col]; bt[nt] = beta[col];
        int d = col & 63;
        as_[nt] = a[d]; ad_[nt] = a[64 + d];
    }

    float pes[4], ped[4];
#pragma unroll
    for (int reg = 0; reg < 4; ++reg) {
        int row = quad * 4 + reg;
        float sum8 = 0.f, sq8 = 0.f;
#pragma unroll
        for (int q = 0; q < 8; ++q) { sum8 += sumL[q][row]; sq8 += sqL[q][row]; }
        float mean = sum8 * (1.f / 256.f);
        float msq  = sq8 * (1.f / 256.f);
        float inv = rsqrtf(msq - mean * mean + 1e-5f);
        float es = 0.f, ed = 0.f;
#pragma unroll
        for (int nt = 0; nt < 2; ++nt) {
            float hn = (acc[nt][reg] - mean) * inv * g[nt] + bt[nt];
            As[row * 264 + w * 32 + nt * 16 + l15] = (unsigned short)f2bf(hn);
            es = fmaf(hn, as_[nt], es);
            ed = fmaf(hn, ad_[nt], ed);
        }
        pes[reg] = es; ped[reg] = ed;
    }
#pragma unroll
    for (int reg = 0; reg < 4; ++reg) {
#pragma unroll
        for (int off = 1; off < 16; off <<= 1) {
            pes[reg] += __shfl_xor(pes[reg], off);
            ped[reg] += __shfl_xor(ped[reg], off);
        }
    }
    if (l15 == 0) {
#pragma unroll
        for (int reg = 0; reg < 4; ++reg) {
            pesL[w][quad * 4 + reg] = pes[reg];
            pedL[w][quad * 4 + reg] = ped[reg];
        }
    }
    __syncthreads();

    // e combine: head h = w>>1 spans waves 2h, 2h+1. 64 threads cover 16 rows x 4 heads.
    if (t < 64) {
        int h = t >> 4, row = t & 15;
        int rowg = m0 + row;
        e_src[rowg * NH + h] = pesL[2 * h][row] + pesL[2 * h + 1][row];
        e_dst[rowg * NH + h] = pedL[2 * h][row] + pedL[2 * h + 1][row];
    }

    // coalesced bf16 h write-out (512 short8s, one per thread)
    {
        int row = t >> 5, cg = t & 31;
        short8 s = *(short8*)&As[row * 264 + cg * 8];
        *(short8*)&hb[(size_t)(m0 + row) * FOUT + cg * 8] = s;
    }
}

// ---------------- Kernel 2: SPARSE attention, XCD-pinned batches, nt adj stream ------
// 1-D grid of 2048 blocks; b = blk & 7 so (with round-robin block->XCD dispatch) each
// XCD serves ONE batch: its hb gather slice is 512 KB and stays L2-resident. adj is
// read-once -> non-temporal loads so the 33.5 MB stream doesn't evict the hb slice.
__global__ __launch_bounds__(256) void k_attn(const unsigned short* __restrict__ hb,
                                              const float* __restrict__ adj,
                                              const float* __restrict__ e_src,
                                              const float* __restrict__ e_dst,
                                              float* __restrict__ out) {
    __shared__ int jlist[4][CAP];
    __shared__ floatx4 wsl[4][CAP];

    const int blk = blockIdx.x;
    const int b = blk & 7;
    const int gidx = blk >> 3;              // 0..255
    const int t = threadIdx.x;
    const int lane = t & 63;
    const int w = t >> 6;
    const int i = gidx * 4 + w;
    const unsigned short* hp = hb + (size_t)b * NN * FOUT;
    const float* adjp = adj + ((size_t)b * NN + i) * NN;
    const float* edp  = e_dst + (size_t)b * NN * NH;
    const float4 esv = *(const float4*)&e_src[((size_t)b * NN + i) * NH];

    int* jl = jlist[w];
    floatx4* wl = wsl[w];

    // Phase 1: all adj loads up-front (non-temporal), then 16 ballot rounds.
    floatx4 av[4];
#pragma unroll
    for (int c = 0; c < 4; ++c)
        av[c] = __builtin_nontemporal_load((const floatx4*)&adjp[c * 256 + lane * 4]);

    int cnt = 0;
#pragma unroll
    for (int c = 0; c < 4; ++c) {
        float am[4] = {av[c][0], av[c][1], av[c][2], av[c][3]};
#pragma unroll
        for (int q = 0; q < 4; ++q) {
            bool nz = (am[q] != 0.0f);
            unsigned long long mask = __ballot(nz);
            if (nz) {
                int pos = cnt + __popcll(mask & ((1ull << lane) - 1ull));
                int j = c * 256 + lane * 4 + q;
                float4 ed = *(const float4*)&edp[(size_t)j * NH];
                float e0 = esv.x + ed.x, e1 = esv.y + ed.y;
                float e2 = esv.z + ed.z, e3 = esv.w + ed.w;
                e0 = e0 > 0.f ? e0 : 0.2f * e0;
                e1 = e1 > 0.f ? e1 : 0.2f * e1;
                e2 = e2 > 0.f ? e2 : 0.2f * e2;
                e3 = e3 > 0.f ? e3 : 0.2f * e3;
                floatx4 w4;
                w4[0] = __expf(e0); w4[1] = __expf(e1);
                w4[2] = __expf(e2); w4[3] = __expf(e3);
                jl[pos] = j;
                wl[pos] = w4;
            }
            cnt += (int)__popcll(mask);
        }
    }
    // wave-private LDS: same-wave write->read, compiler inserts lgkmcnt; no barrier.

    // Phase 2: full row per wave; lane owns features [lane*4, lane*4+4), head = lane>>4
    const int hh = lane >> 4;
    float4 acc = make_float4(0.f, 0.f, 0.f, 0.f);
    float S = 0.f;

    int idx = 0;
    for (; idx + 4 <= cnt; idx += 4) {
        int jj[4]; float wv[4]; short4v hv[4];
#pragma unroll
        for (int q = 0; q < 4; ++q) {
            jj[q] = jl[idx + q];
            wv[q] = ((const float*)&wl[idx + q])[hh];
        }
#pragma unroll
        for (int q = 0; q < 4; ++q)
            hv[q] = *(const short4v*)&hp[(size_t)jj[q] * FOUT + lane * 4];
#pragma unroll
        for (int q = 0; q < 4; ++q) {
            acc.x = fmaf(wv[q], bf2f((unsigned short)hv[q].x), acc.x);
            acc.y = fmaf(wv[q], bf2f((unsigned short)hv[q].y), acc.y);
            acc.z = fmaf(wv[q], bf2f((unsigned short)hv[q].z), acc.z);
            acc.w = fmaf(wv[q], bf2f((unsigned short)hv[q].w), acc.w);
            S += wv[q];
        }
    }
    for (; idx < cnt; ++idx) {
        int j = jl[idx];
        float wv = ((const float*)&wl[idx])[hh];
        short4v hv = *(const short4v*)&hp[(size_t)j * FOUT + lane * 4];
        acc.x = fmaf(wv, bf2f((unsigned short)hv.x), acc.x);
        acc.y = fmaf(wv, bf2f((unsigned short)hv.y), acc.y);
        acc.z = fmaf(wv, bf2f((unsigned short)hv.z), acc.z);
        acc.w = fmaf(wv, bf2f((unsigned short)hv.w), acc.w);
        S += wv;
    }

    float inv = 1.0f / S;
    floatx4 o;
    o[0] = acc.x * inv; o[1] = acc.y * inv; o[2] = acc.z * inv; o[3] = acc.w * inv;
    __builtin_nontemporal_store(o, (floatx4*)&out[((size_t)b * NN + i) * FOUT + lane * 4]);
}

extern "C" void kernel_launch(void* const* d_in, const int* in_sizes, int n_in,
                              void* d_out, int out_size, void* d_ws, size_t ws_size,
                              hipStream_t stream) {
    const float* x     = (const float*)d_in[0];
    const float* adj   = (const float*)d_in[1];
    const float* W     = (const float*)d_in[2];
    const float* gamma = (const float*)d_in[3];
    const float* beta  = (const float*)d_in[4];
    const float* a     = (const float*)d_in[5];
    float* out = (float*)d_out;

    unsigned short* Wt = (unsigned short*)d_ws;                 // 256*256 bf16 (128 KB)
    unsigned short* hb = Wt + (size_t)FIN * FOUT;               // 8*1024*256 bf16 (4 MB)
    float* e_src = (float*)(hb + (size_t)BB * NN * FOUT);       // 8192*4 fp32
    float* e_dst = e_src + (size_t)BB * NN * NH;

    k_wt<<<dim3(4, 4), 256, 0, stream>>>(W, Wt);
    k_gemm_ln<<<dim3(512), 512, 0, stream>>>(x, Wt, gamma, beta, a, hb, e_src, e_dst);
    k_attn<<<dim3(2048), 256, 0, stream>>>(hb, adj, e_src, e_dst, out);
}

// Round 6
// 115.371 us; speedup vs baseline: 1.0673x; 1.0673x over previous
//
#include <hip/hip_runtime.h>
#include <hip/hip_bf16.h>

#define BB 8
#define NN 1024
#define FIN 256
#define FOUT 256
#define NH 4
#define CAP 192    // max nnz per adjacency row (mean 51, 20 sigma margin)

typedef short short8 __attribute__((ext_vector_type(8)));
typedef short short4v __attribute__((ext_vector_type(4)));
typedef float floatx4 __attribute__((ext_vector_type(4)));

__device__ __forceinline__ short f2bf(float f) {
    unsigned int u = __builtin_bit_cast(unsigned int, f);
    unsigned int r = (u + 0x7fffu + ((u >> 16) & 1u)) >> 16;   // RNE
    return (short)r;
}
__device__ __forceinline__ float bf2f(unsigned short s) {
    return __builtin_bit_cast(float, (unsigned int)s << 16);
}

// ---------------- Kernel 0: Wt[n][k] = bf16(W[k][n])  (256x256, 128 KB out) ----------
__global__ __launch_bounds__(256) void k_wt(const float* __restrict__ W,
                                            unsigned short* __restrict__ Wt) {
    __shared__ unsigned short ts[64][80];   // [n][k], pad 80 -> 16B-aligned rows
    const int k0 = blockIdx.x * 64, n0 = blockIdx.y * 64;
    const int t = threadIdx.x;
#pragma unroll
    for (int q = 0; q < 4; ++q) {
        int lin = t + q * 256;              // 0..1023 float4s
        int r = lin >> 4, c4 = lin & 15;    // r = k row, c4 = n group
        float4 v = *(const float4*)&W[(size_t)(k0 + r) * FOUT + n0 + c4 * 4];
        ts[c4 * 4 + 0][r] = (unsigned short)f2bf(v.x);
        ts[c4 * 4 + 1][r] = (unsigned short)f2bf(v.y);
        ts[c4 * 4 + 2][r] = (unsigned short)f2bf(v.z);
        ts[c4 * 4 + 3][r] = (unsigned short)f2bf(v.w);
    }
    __syncthreads();
#pragma unroll
    for (int q = 0; q < 2; ++q) {
        int lin = t + q * 256;              // 0..511 short8s
        int row = lin >> 3, kg = lin & 7;
        short8 s = *(short8*)&ts[row][kg * 8];
        *(short8*)&Wt[(size_t)(n0 + row) * FIN + k0 + kg * 8] = s;
    }
}

// ---------------- Kernel 1: fused h=x@W (bf16 MFMA) + LayerNorm + e_src/e_dst --------
// Block: 16 rows x 256 cols, 512 threads (8 waves). Wave w owns cols [32w,32w+32).
__global__ __launch_bounds__(512) void k_gemm_ln(const float* __restrict__ x,
                                                 const unsigned short* __restrict__ Wt,
                                                 const float* __restrict__ gamma,
                                                 const float* __restrict__ beta,
                                                 const float* __restrict__ a,
                                                 unsigned short* __restrict__ hb,
                                                 float* __restrict__ e_src,
                                                 float* __restrict__ e_dst) {
    __shared__ unsigned short As[16 * 264];   // [m][k] stride 264 (8.4 KB)
    __shared__ float sumL[8][16], sqL[8][16];
    __shared__ float pesL[8][16], pedL[8][16];
    const int m0 = blockIdx.x * 16;
    const int t = threadIdx.x;
    const int w = t >> 6, lane = t & 63, quad = lane >> 4, l15 = lane & 15;

    // stage A: 16 x 256 fp32 -> bf16 (coalesced float4)
#pragma unroll
    for (int q = 0; q < 2; ++q) {
        int lin = t + q * 512;               // 0..1023 float4
        int row = lin >> 6, c4 = lin & 63;
        float4 v = *(const float4*)&x[(size_t)(m0 + row) * FIN + c4 * 4];
        short4v s;
        s.x = f2bf(v.x); s.y = f2bf(v.y); s.z = f2bf(v.z); s.w = f2bf(v.w);
        *(short4v*)&As[row * 264 + c4 * 4] = s;
    }
    __syncthreads();

    floatx4 acc[2];
#pragma unroll
    for (int nt = 0; nt < 2; ++nt) acc[nt] = (floatx4)0.f;

#pragma unroll
    for (int ks = 0; ks < 8; ++ks) {
        short8 af = *(short8*)&As[l15 * 264 + ks * 32 + quad * 8];
#pragma unroll
        for (int nt = 0; nt < 2; ++nt) {
            short8 bf = *(const short8*)&Wt[(size_t)((w * 2 + nt) * 16 + l15) * FIN + ks * 32 + quad * 8];
            acc[nt] = __builtin_amdgcn_mfma_f32_16x16x32_bf16(af, bf, acc[nt], 0, 0, 0);
        }
    }

    // per-wave LN partials: row = quad*4+reg, this wave's 32 cols
    float rs[4], rq[4];
#pragma unroll
    for (int reg = 0; reg < 4; ++reg) {
        float s = 0.f, q2 = 0.f;
#pragma unroll
        for (int nt = 0; nt < 2; ++nt) { float v = acc[nt][reg]; s += v; q2 = fmaf(v, v, q2); }
#pragma unroll
        for (int off = 1; off < 16; off <<= 1) { s += __shfl_xor(s, off); q2 += __shfl_xor(q2, off); }
        rs[reg] = s; rq[reg] = q2;
    }
    if (l15 == 0) {
#pragma unroll
        for (int reg = 0; reg < 4; ++reg) {
            sumL[w][quad * 4 + reg] = rs[reg];
            sqL[w][quad * 4 + reg] = rq[reg];
        }
    }
    __syncthreads();   // also separates K-loop As reads from hn overwrite below

    float g[2], bt[2], as_[2], ad_[2];
#pragma unroll
    for (int nt = 0; nt < 2; ++nt) {
        int col = w * 32 + nt * 16 + l15;
        g[nt] = gamma[col]; bt[nt] = beta[col];
        int d = col & 63;
        as_[nt] = a[d]; ad_[nt] = a[64 + d];
    }

    float pes[4], ped[4];
#pragma unroll
    for (int reg = 0; reg < 4; ++reg) {
        int row = quad * 4 + reg;
        float sum8 = 0.f, sq8 = 0.f;
#pragma unroll
        for (int q = 0; q < 8; ++q) { sum8 += sumL[q][row]; sq8 += sqL[q][row]; }
        float mean = sum8 * (1.f / 256.f);
        float msq  = sq8 * (1.f / 256.f);
        float inv = rsqrtf(msq - mean * mean + 1e-5f);
        float es = 0.f, ed = 0.f;
#pragma unroll
        for (int nt = 0; nt < 2; ++nt) {
            float hn = (acc[nt][reg] - mean) * inv * g[nt] + bt[nt];
            As[row * 264 + w * 32 + nt * 16 + l15] = (unsigned short)f2bf(hn);
            es = fmaf(hn, as_[nt], es);
            ed = fmaf(hn, ad_[nt], ed);
        }
        pes[reg] = es; ped[reg] = ed;
    }
#pragma unroll
    for (int reg = 0; reg < 4; ++reg) {
#pragma unroll
        for (int off = 1; off < 16; off <<= 1) {
            pes[reg] += __shfl_xor(pes[reg], off);
            ped[reg] += __shfl_xor(ped[reg], off);
        }
    }
    if (l15 == 0) {
#pragma unroll
        for (int reg = 0; reg < 4; ++reg) {
            pesL[w][quad * 4 + reg] = pes[reg];
            pedL[w][quad * 4 + reg] = ped[reg];
        }
    }
    __syncthreads();

    // e combine: head h = w>>1 spans waves 2h, 2h+1. 64 threads cover 16 rows x 4 heads.
    if (t < 64) {
        int h = t >> 4, row = t & 15;
        int rowg = m0 + row;
        e_src[rowg * NH + h] = pesL[2 * h][row] + pesL[2 * h + 1][row];
        e_dst[rowg * NH + h] = pedL[2 * h][row] + pedL[2 * h + 1][row];
    }

    // coalesced bf16 h write-out (512 short8s, one per thread)
    {
        int row = t >> 5, cg = t & 31;
        short8 s = *(short8*)&As[row * 264 + cg * 8];
        *(short8*)&hb[(size_t)(m0 + row) * FOUT + cg * 8] = s;
    }
}

// ---------------- Kernel 2: SPARSE attention, ONE WAVE PER ROW, split compaction -----
// Phase 1a: cheap j-only ballot compaction (~7 insts/round instead of ~25).
// Phase 1b: ONE vectorized pass computes all weights (lane p -> entry p), batching
// the ~51 scattered e_dst loads into a single issue window.
__global__ __launch_bounds__(256) void k_attn(const unsigned short* __restrict__ hb,
                                              const float* __restrict__ adj,
                                              const float* __restrict__ e_src,
                                              const float* __restrict__ e_dst,
                                              float* __restrict__ out) {
    __shared__ int jlist[4][CAP];
    __shared__ float4 wsl[4][CAP];

    const int b = blockIdx.y;
    const int t = threadIdx.x;
    const int lane = t & 63;
    const int w = t >> 6;
    const int i = blockIdx.x * 4 + w;
    const unsigned short* hp = hb + (size_t)b * NN * FOUT;
    const float* adjp = adj + ((size_t)b * NN + i) * NN;
    const float* edp  = e_dst + (size_t)b * NN * NH;
    const float4 esv = *(const float4*)&e_src[((size_t)b * NN + i) * NH];

    int* jl = jlist[w];
    float4* wl = wsl[w];

    // Phase 1a: adj loads up-front (one HBM latency), then 16 j-only ballot rounds.
    float4 av[4];
#pragma unroll
    for (int c = 0; c < 4; ++c)
        av[c] = *(const float4*)&adjp[c * 256 + lane * 4];

    int cnt = 0;
#pragma unroll
    for (int c = 0; c < 4; ++c) {
        float am[4] = {av[c].x, av[c].y, av[c].z, av[c].w};
#pragma unroll
        for (int q = 0; q < 4; ++q) {
            bool nz = (am[q] != 0.0f);
            unsigned long long mask = __ballot(nz);
            if (nz) {
                int pos = cnt + __popcll(mask & ((1ull << lane) - 1ull));
                jl[pos] = c * 256 + lane * 4 + q;
            }
            cnt += (int)__popcll(mask);
        }
    }
    // wave-private LDS: same-wave write->read, compiler inserts lgkmcnt; no barrier.

    // Phase 1b: vectorized weight pass — lane p handles entry p (cnt ~51, 1 pass).
#pragma unroll 1
    for (int p = lane; p < cnt; p += 64) {
        int j = jl[p];
        float4 ed = *(const float4*)&edp[(size_t)j * NH];
        float e0 = esv.x + ed.x, e1 = esv.y + ed.y;
        float e2 = esv.z + ed.z, e3 = esv.w + ed.w;
        e0 = e0 > 0.f ? e0 : 0.2f * e0;
        e1 = e1 > 0.f ? e1 : 0.2f * e1;
        e2 = e2 > 0.f ? e2 : 0.2f * e2;
        e3 = e3 > 0.f ? e3 : 0.2f * e3;
        float4 w4;
        w4.x = __expf(e0); w4.y = __expf(e1);
        w4.z = __expf(e2); w4.w = __expf(e3);
        wl[p] = w4;
    }

    // Phase 2: full row per wave; lane owns features [lane*4, lane*4+4), head = lane>>4
    const int hh = lane >> 4;
    float4 acc = make_float4(0.f, 0.f, 0.f, 0.f);
    float S = 0.f;

    int idx = 0;
    for (; idx + 4 <= cnt; idx += 4) {
        int jj[4]; float wv[4]; short4v hv[4];
#pragma unroll
        for (int q = 0; q < 4; ++q) {
            jj[q] = jl[idx + q];
            wv[q] = ((const float*)&wl[idx + q])[hh];
        }
#pragma unroll
        for (int q = 0; q < 4; ++q)
            hv[q] = *(const short4v*)&hp[(size_t)jj[q] * FOUT + lane * 4];
#pragma unroll
        for (int q = 0; q < 4; ++q) {
            acc.x = fmaf(wv[q], bf2f((unsigned short)hv[q].x), acc.x);
            acc.y = fmaf(wv[q], bf2f((unsigned short)hv[q].y), acc.y);
            acc.z = fmaf(wv[q], bf2f((unsigned short)hv[q].z), acc.z);
            acc.w = fmaf(wv[q], bf2f((unsigned short)hv[q].w), acc.w);
            S += wv[q];
        }
    }
    for (; idx < cnt; ++idx) {
        int j = jl[idx];
        float wv = ((const float*)&wl[idx])[hh];
        short4v hv = *(const short4v*)&hp[(size_t)j * FOUT + lane * 4];
        acc.x = fmaf(wv, bf2f((unsigned short)hv.x), acc.x);
        acc.y = fmaf(wv, bf2f((unsigned short)hv.y), acc.y);
        acc.z = fmaf(wv, bf2f((unsigned short)hv.z), acc.z);
        acc.w = fmaf(wv, bf2f((unsigned short)hv.w), acc.w);
        S += wv;
    }

    float inv = 1.0f / S;
    float4 o;
    o.x = acc.x * inv; o.y = acc.y * inv; o.z = acc.z * inv; o.w = acc.w * inv;
    *(float4*)&out[((size_t)b * NN + i) * FOUT + lane * 4] = o;
}

extern "C" void kernel_launch(void* const* d_in, const int* in_sizes, int n_in,
                              void* d_out, int out_size, void* d_ws, size_t ws_size,
                              hipStream_t stream) {
    const float* x     = (const float*)d_in[0];
    const float* adj   = (const float*)d_in[1];
    const float* W     = (const float*)d_in[2];
    const float* gamma = (const float*)d_in[3];
    const float* beta  = (const float*)d_in[4];
    const float* a     = (const float*)d_in[5];
    float* out = (float*)d_out;

    unsigned short* Wt = (unsigned short*)d_ws;                 // 256*256 bf16 (128 KB)
    unsigned short* hb = Wt + (size_t)FIN * FOUT;               // 8*1024*256 bf16 (4 MB)
    float* e_src = (float*)(hb + (size_t)BB * NN * FOUT);       // 8192*4 fp32
    float* e_dst = e_src + (size_t)BB * NN * NH;

    k_wt<<<dim3(4, 4), 256, 0, stream>>>(W, Wt);
    k_gemm_ln<<<dim3(512), 512, 0, stream>>>(x, Wt, gamma, beta, a, hb, e_src, e_dst);
    k_attn<<<dim3(NN / 4, BB), 256, 0, stream>>>(hb, adj, e_src, e_dst, out);
}

// Round 7
// 112.267 us; speedup vs baseline: 1.0968x; 1.0276x over previous
//
#include <hip/hip_runtime.h>
#include <hip/hip_bf16.h>

#define BB 8
#define NN 1024
#define FIN 256
#define FOUT 256
#define NH 4
#define CAP 192    // max nnz per adjacency row (mean 51, 20 sigma margin)

typedef short short8 __attribute__((ext_vector_type(8)));
typedef short short4v __attribute__((ext_vector_type(4)));
typedef float floatx4 __attribute__((ext_vector_type(4)));

__device__ __forceinline__ short f2bf(float f) {
    unsigned int u = __builtin_bit_cast(unsigned int, f);
    unsigned int r = (u + 0x7fffu + ((u >> 16) & 1u)) >> 16;   // RNE
    return (short)r;
}
__device__ __forceinline__ float bf2f(unsigned short s) {
    return __builtin_bit_cast(float, (unsigned int)s << 16);
}

// ---------------- Kernel 0: Wt[n][k] = bf16(W[k][n])  (256x256, 128 KB out) ----------
__global__ __launch_bounds__(256) void k_wt(const float* __restrict__ W,
                                            unsigned short* __restrict__ Wt) {
    __shared__ unsigned short ts[64][80];   // [n][k], pad 80 -> 16B-aligned rows
    const int k0 = blockIdx.x * 64, n0 = blockIdx.y * 64;
    const int t = threadIdx.x;
#pragma unroll
    for (int q = 0; q < 4; ++q) {
        int lin = t + q * 256;              // 0..1023 float4s
        int r = lin >> 4, c4 = lin & 15;    // r = k row, c4 = n group
        float4 v = *(const float4*)&W[(size_t)(k0 + r) * FOUT + n0 + c4 * 4];
        ts[c4 * 4 + 0][r] = (unsigned short)f2bf(v.x);
        ts[c4 * 4 + 1][r] = (unsigned short)f2bf(v.y);
        ts[c4 * 4 + 2][r] = (unsigned short)f2bf(v.z);
        ts[c4 * 4 + 3][r] = (unsigned short)f2bf(v.w);
    }
    __syncthreads();
#pragma unroll
    for (int q = 0; q < 2; ++q) {
        int lin = t + q * 256;              // 0..511 short8s
        int row = lin >> 3, kg = lin & 7;
        short8 s = *(short8*)&ts[row][kg * 8];
        *(short8*)&Wt[(size_t)(n0 + row) * FIN + k0 + kg * 8] = s;
    }
}

// ---------------- Kernel 1: fused h=x@W (bf16 MFMA) + LayerNorm + e_src/e_dst --------
// Block: 16 rows x 256 cols, 512 threads (8 waves). Wave w owns cols [32w,32w+32).
__global__ __launch_bounds__(512) void k_gemm_ln(const float* __restrict__ x,
                                                 const unsigned short* __restrict__ Wt,
                                                 const float* __restrict__ gamma,
                                                 const float* __restrict__ beta,
                                                 const float* __restrict__ a,
                                                 unsigned short* __restrict__ hb,
                                                 float* __restrict__ e_src,
                                                 float* __restrict__ e_dst) {
    __shared__ unsigned short As[16 * 264];   // [m][k] stride 264 (8.4 KB)
    __shared__ float sumL[8][16], sqL[8][16];
    __shared__ float pesL[8][16], pedL[8][16];
    const int m0 = blockIdx.x * 16;
    const int t = threadIdx.x;
    const int w = t >> 6, lane = t & 63, quad = lane >> 4, l15 = lane & 15;

    // stage A: 16 x 256 fp32 -> bf16 (coalesced float4)
#pragma unroll
    for (int q = 0; q < 2; ++q) {
        int lin = t + q * 512;               // 0..1023 float4
        int row = lin >> 6, c4 = lin & 63;
        float4 v = *(const float4*)&x[(size_t)(m0 + row) * FIN + c4 * 4];
        short4v s;
        s.x = f2bf(v.x); s.y = f2bf(v.y); s.z = f2bf(v.z); s.w = f2bf(v.w);
        *(short4v*)&As[row * 264 + c4 * 4] = s;
    }
    __syncthreads();

    floatx4 acc[2];
#pragma unroll
    for (int nt = 0; nt < 2; ++nt) acc[nt] = (floatx4)0.f;

#pragma unroll
    for (int ks = 0; ks < 8; ++ks) {
        short8 af = *(short8*)&As[l15 * 264 + ks * 32 + quad * 8];
#pragma unroll
        for (int nt = 0; nt < 2; ++nt) {
            short8 bf = *(const short8*)&Wt[(size_t)((w * 2 + nt) * 16 + l15) * FIN + ks * 32 + quad * 8];
            acc[nt] = __builtin_amdgcn_mfma_f32_16x16x32_bf16(af, bf, acc[nt], 0, 0, 0);
        }
    }

    // per-wave LN partials: row = quad*4+reg, this wave's 32 cols
    float rs[4], rq[4];
#pragma unroll
    for (int reg = 0; reg < 4; ++reg) {
        float s = 0.f, q2 = 0.f;
#pragma unroll
        for (int nt = 0; nt < 2; ++nt) { float v = acc[nt][reg]; s += v; q2 = fmaf(v, v, q2); }
#pragma unroll
        for (int off = 1; off < 16; off <<= 1) { s += __shfl_xor(s, off); q2 += __shfl_xor(q2, off); }
        rs[reg] = s; rq[reg] = q2;
    }
    if (l15 == 0) {
#pragma unroll
        for (int reg = 0; reg < 4; ++reg) {
            sumL[w][quad * 4 + reg] = rs[reg];
            sqL[w][quad * 4 + reg] = rq[reg];
        }
    }
    __syncthreads();   // also separates K-loop As reads from hn overwrite below

    float g[2], bt[2], as_[2], ad_[2];
#pragma unroll
    for (int nt = 0; nt < 2; ++nt) {
        int col = w * 32 + nt * 16 + l15;
        g[nt] = gamma[col]; bt[nt] = beta[col];
        int d = col & 63;
        as_[nt] = a[d]; ad_[nt] = a[64 + d];
    }

    float pes[4], ped[4];
#pragma unroll
    for (int reg = 0; reg < 4; ++reg) {
        int row = quad * 4 + reg;
        float sum8 = 0.f, sq8 = 0.f;
#pragma unroll
        for (int q = 0; q < 8; ++q) { sum8 += sumL[q][row]; sq8 += sqL[q][row]; }
        float mean = sum8 * (1.f / 256.f);
        float msq  = sq8 * (1.f / 256.f);
        float inv = rsqrtf(msq - mean * mean + 1e-5f);
        float es = 0.f, ed = 0.f;
#pragma unroll
        for (int nt = 0; nt < 2; ++nt) {
            float hn = (acc[nt][reg] - mean) * inv * g[nt] + bt[nt];
            As[row * 264 + w * 32 + nt * 16 + l15] = (unsigned short)f2bf(hn);
            es = fmaf(hn, as_[nt], es);
            ed = fmaf(hn, ad_[nt], ed);
        }
        pes[reg] = es; ped[reg] = ed;
    }
#pragma unroll
    for (int reg = 0; reg < 4; ++reg) {
#pragma unroll
        for (int off = 1; off < 16; off <<= 1) {
            pes[reg] += __shfl_xor(pes[reg], off);
            ped[reg] += __shfl_xor(ped[reg], off);
        }
    }
    if (l15 == 0) {
#pragma unroll
        for (int reg = 0; reg < 4; ++reg) {
            pesL[w][quad * 4 + reg] = pes[reg];
            pedL[w][quad * 4 + reg] = ped[reg];
        }
    }
    __syncthreads();

    // e combine: head h = w>>1 spans waves 2h, 2h+1. 64 threads cover 16 rows x 4 heads.
    if (t < 64) {
        int h = t >> 4, row = t & 15;
        int rowg = m0 + row;
        e_src[rowg * NH + h] = pesL[2 * h][row] + pesL[2 * h + 1][row];
        e_dst[rowg * NH + h] = pedL[2 * h][row] + pedL[2 * h + 1][row];
    }

    // coalesced bf16 h write-out (512 short8s, one per thread)
    {
        int row = t >> 5, cg = t & 31;
        short8 s = *(short8*)&As[row * 264 + cg * 8];
        *(short8*)&hb[(size_t)(m0 + row) * FOUT + cg * 8] = s;
    }
}

// ---------------- Kernel 2: SPARSE attention, 32 lanes per entry, split compaction ---
// Phase 1a: j-only ballot compaction. Phase 1b: one vectorized weight pass.
// Phase 2: lane halves process entries p/p+1; lane owns 8 features (16B loads);
// cross-half combine via shfl_xor(32).
__global__ __launch_bounds__(256) void k_attn(const unsigned short* __restrict__ hb,
                                              const float* __restrict__ adj,
                                              const float* __restrict__ e_src,
                                              const float* __restrict__ e_dst,
                                              float* __restrict__ out) {
    __shared__ int jlist[4][CAP];
    __shared__ float4 wsl[4][CAP];

    const int b = blockIdx.y;
    const int t = threadIdx.x;
    const int lane = t & 63;
    const int w = t >> 6;
    const int i = blockIdx.x * 4 + w;
    const unsigned short* hp = hb + (size_t)b * NN * FOUT;
    const float* adjp = adj + ((size_t)b * NN + i) * NN;
    const float* edp  = e_dst + (size_t)b * NN * NH;
    const float4 esv = *(const float4*)&e_src[((size_t)b * NN + i) * NH];

    int* jl = jlist[w];
    float4* wl = wsl[w];

    // Phase 1a: adj loads up-front (one HBM latency), then 16 j-only ballot rounds.
    float4 av[4];
#pragma unroll
    for (int c = 0; c < 4; ++c)
        av[c] = *(const float4*)&adjp[c * 256 + lane * 4];

    int cnt = 0;
#pragma unroll
    for (int c = 0; c < 4; ++c) {
        float am[4] = {av[c].x, av[c].y, av[c].z, av[c].w};
#pragma unroll
        for (int q = 0; q < 4; ++q) {
            bool nz = (am[q] != 0.0f);
            unsigned long long mask = __ballot(nz);
            if (nz) {
                int pos = cnt + __popcll(mask & ((1ull << lane) - 1ull));
                jl[pos] = c * 256 + lane * 4 + q;
            }
            cnt += (int)__popcll(mask);
        }
    }
    // wave-private LDS: same-wave write->read, compiler inserts lgkmcnt; no barrier.

    // Phase 1b: vectorized weight pass — lane p handles entry p (cnt ~51, 1 pass).
#pragma unroll 1
    for (int p = lane; p < cnt; p += 64) {
        int j = jl[p];
        float4 ed = *(const float4*)&edp[(size_t)j * NH];
        float e0 = esv.x + ed.x, e1 = esv.y + ed.y;
        float e2 = esv.z + ed.z, e3 = esv.w + ed.w;
        e0 = e0 > 0.f ? e0 : 0.2f * e0;
        e1 = e1 > 0.f ? e1 : 0.2f * e1;
        e2 = e2 > 0.f ? e2 : 0.2f * e2;
        e3 = e3 > 0.f ? e3 : 0.2f * e3;
        float4 w4;
        w4.x = __expf(e0); w4.y = __expf(e1);
        w4.z = __expf(e2); w4.w = __expf(e3);
        wl[p] = w4;
    }

    // Phase 2: 32 lanes per entry. half = lane>>5 picks entry p+half; lane owns
    // features [fg*8, fg*8+8) (16B short8 loads, same 512 B/entry, half the loads).
    const int half = lane >> 5;
    const int fg = lane & 31;
    const int hh = fg >> 3;                 // head of this 8-feature group
    float a0=0.f,a1=0.f,a2=0.f,a3=0.f,a4=0.f,a5=0.f,a6=0.f,a7=0.f;
    float S = 0.f;

    int p = 0;
    for (; p + 8 <= cnt; p += 8) {
        int jj[4]; float wv[4]; short8 hv[4];
#pragma unroll
        for (int q = 0; q < 4; ++q) {
            int e = p + 2 * q + half;
            jj[q] = jl[e];
            wv[q] = ((const float*)&wl[e])[hh];
        }
#pragma unroll
        for (int q = 0; q < 4; ++q)
            hv[q] = *(const short8*)&hp[(size_t)jj[q] * FOUT + fg * 8];
#pragma unroll
        for (int q = 0; q < 4; ++q) {
            a0 = fmaf(wv[q], bf2f((unsigned short)hv[q][0]), a0);
            a1 = fmaf(wv[q], bf2f((unsigned short)hv[q][1]), a1);
            a2 = fmaf(wv[q], bf2f((unsigned short)hv[q][2]), a2);
            a3 = fmaf(wv[q], bf2f((unsigned short)hv[q][3]), a3);
            a4 = fmaf(wv[q], bf2f((unsigned short)hv[q][4]), a4);
            a5 = fmaf(wv[q], bf2f((unsigned short)hv[q][5]), a5);
            a6 = fmaf(wv[q], bf2f((unsigned short)hv[q][6]), a6);
            a7 = fmaf(wv[q], bf2f((unsigned short)hv[q][7]), a7);
            S += wv[q];
        }
    }
    for (; p + 2 <= cnt; p += 2) {          // pair tail
        int e = p + half;
        int j = jl[e];
        float wv = ((const float*)&wl[e])[hh];
        short8 hv = *(const short8*)&hp[(size_t)j * FOUT + fg * 8];
        a0 = fmaf(wv, bf2f((unsigned short)hv[0]), a0);
        a1 = fmaf(wv, bf2f((unsigned short)hv[1]), a1);
        a2 = fmaf(wv, bf2f((unsigned short)hv[2]), a2);
        a3 = fmaf(wv, bf2f((unsigned short)hv[3]), a3);
        a4 = fmaf(wv, bf2f((unsigned short)hv[4]), a4);
        a5 = fmaf(wv, bf2f((unsigned short)hv[5]), a5);
        a6 = fmaf(wv, bf2f((unsigned short)hv[6]), a6);
        a7 = fmaf(wv, bf2f((unsigned short)hv[7]), a7);
        S += wv;
    }
    if (p < cnt && half == 0) {             // single tail: half 0 only
        int j = jl[p];
        float wv = ((const float*)&wl[p])[hh];
        short8 hv = *(const short8*)&hp[(size_t)j * FOUT + fg * 8];
        a0 = fmaf(wv, bf2f((unsigned short)hv[0]), a0);
        a1 = fmaf(wv, bf2f((unsigned short)hv[1]), a1);
        a2 = fmaf(wv, bf2f((unsigned short)hv[2]), a2);
        a3 = fmaf(wv, bf2f((unsigned short)hv[3]), a3);
        a4 = fmaf(wv, bf2f((unsigned short)hv[4]), a4);
        a5 = fmaf(wv, bf2f((unsigned short)hv[5]), a5);
        a6 = fmaf(wv, bf2f((unsigned short)hv[6]), a6);
        a7 = fmaf(wv, bf2f((unsigned short)hv[7]), a7);
        S += wv;
    }

    // combine halves (entry-parity partials) across lane^32
    S  += __shfl_xor(S, 32);
    a0 += __shfl_xor(a0, 32); a1 += __shfl_xor(a1, 32);
    a2 += __shfl_xor(a2, 32); a3 += __shfl_xor(a3, 32);
    a4 += __shfl_xor(a4, 32); a5 += __shfl_xor(a5, 32);
    a6 += __shfl_xor(a6, 32); a7 += __shfl_xor(a7, 32);

    float inv = 1.0f / S;
    float4 o;                               // compile-time indices only (no scratch)
    o.x = (half ? a4 : a0) * inv;
    o.y = (half ? a5 : a1) * inv;
    o.z = (half ? a6 : a2) * inv;
    o.w = (half ? a7 : a3) * inv;
    // half 0 writes feats [fg*8, fg*8+4), half 1 writes [fg*8+4, fg*8+8): full 1KB row
    *(float4*)&out[((size_t)b * NN + i) * FOUT + fg * 8 + half * 4] = o;
}

extern "C" void kernel_launch(void* const* d_in, const int* in_sizes, int n_in,
                              void* d_out, int out_size, void* d_ws, size_t ws_size,
                              hipStream_t stream) {
    const float* x     = (const float*)d_in[0];
    const float* adj   = (const float*)d_in[1];
    const float* W     = (const float*)d_in[2];
    const float* gamma = (const float*)d_in[3];
    const float* beta  = (const float*)d_in[4];
    const float* a     = (const float*)d_in[5];
    float* out = (float*)d_out;

    unsigned short* Wt = (unsigned short*)d_ws;                 // 256*256 bf16 (128 KB)
    unsigned short* hb = Wt + (size_t)FIN * FOUT;               // 8*1024*256 bf16 (4 MB)
    float* e_src = (float*)(hb + (size_t)BB * NN * FOUT);       // 8192*4 fp32
    float* e_dst = e_src + (size_t)BB * NN * NH;

    k_wt<<<dim3(4, 4), 256, 0, stream>>>(W, Wt);
    k_gemm_ln<<<dim3(512), 512, 0, stream>>>(x, Wt, gamma, beta, a, hb, e_src, e_dst);
    k_attn<<<dim3(NN / 4, BB), 256, 0, stream>>>(hb, adj, e_src, e_dst, out);
}